// Round 8
// baseline (408.188 us; speedup 1.0000x reference)
//
#include <hip/hip_runtime.h>

#define BATCH 16
#define PS 784          // nodes per partition; LDS acc = 784*17*4 = 53312 B
#define STRIDE 17       // padded per-node LDS stride (floats) to spread banks
#define NPART 64        // 64*784 = 50176 >= 50001
#define SLICES 8        // accumulate blocks per partition
#define NB (NPART * SLICES)   // 512 blocks = exactly 2/CU
#define TPB 1024

typedef unsigned int uint4v __attribute__((ext_vector_type(4)));
typedef float float4v __attribute__((ext_vector_type(4)));

// fast tanh: 1 - 2/(e^{2z}+1); rel err ~1e-6 vs 2.6e-4 threshold
static __device__ __forceinline__ float fast_tanh(float z) {
    float ez = __expf(2.0f * z);
    return 1.0f - 2.0f * __builtin_amdgcn_rcpf(ez + 1.0f);
}

// aux_T[(N+1)][16]: node-major transpose of x with a zero row at node 0.
__global__ void build_aux_T(const float* __restrict__ x, float* __restrict__ auxT, int n) {
    int idx = blockIdx.x * blockDim.x + threadIdx.x;
    if (idx >= BATCH * n) return;
    int b = idx / n;
    int i = idx % n;
    auxT[(i + 1) * BATCH + b] = x[idx];
    if (idx < BATCH) auxT[idx] = 0.0f;
}

// ---------------- sorted-record path ----------------

__global__ __launch_bounds__(TPB)
void hist_kernel(const int* __restrict__ src, const int* __restrict__ des,
                 unsigned* __restrict__ blockHist, int E) {
    __shared__ unsigned hist[NPART];
    int tid = threadIdx.x;
    for (int i = tid; i < NPART; i += TPB) hist[i] = 0;
    __syncthreads();
    long t = (long)blockIdx.x * TPB + tid;
    long stride = (long)gridDim.x * TPB * 4;
    for (long e0 = t * 4; e0 < E; e0 += stride) {
        int ne = (int)min((long)4, (long)E - e0);
        if (ne == 4) {
            int4 sv = *(const int4*)(src + e0);
            int4 dv = *(const int4*)(des + e0);
            int ss[4] = {sv.x, sv.y, sv.z, sv.w};
            int dd[4] = {dv.x, dv.y, dv.z, dv.w};
#pragma unroll
            for (int j = 0; j < 4; ++j) {
                int ps = ss[j] / PS, pd = dd[j] / PS;
                atomicAdd(&hist[ps], 1u);
                if (pd != ps) atomicAdd(&hist[pd], 1u);
            }
        } else {
            for (int j = 0; j < ne; ++j) {
                int ps = src[e0 + j] / PS, pd = des[e0 + j] / PS;
                atomicAdd(&hist[ps], 1u);
                if (pd != ps) atomicAdd(&hist[pd], 1u);
            }
        }
    }
    __syncthreads();
    if (tid < NPART) blockHist[(size_t)blockIdx.x * NPART + tid] = hist[tid];
}

// One block: exact scatter offsets per (block, partition). NB/16 must be int.
__global__ __launch_bounds__(TPB)
void scan_offsets(const unsigned* __restrict__ blockHist, unsigned* __restrict__ offsets,
                  unsigned* __restrict__ binStartG, unsigned* __restrict__ binTotalG) {
    __shared__ unsigned tot[NPART];
    __shared__ unsigned bstart[NPART];
    int tid = threadIdx.x;
    int team = tid >> 4, j = tid & 15;   // 64 teams of 16 = TPB
    if (team < NPART) {
        unsigned lsum = 0;
        for (int b = j; b < NB; b += 16) lsum += blockHist[(size_t)b * NPART + team];
        for (int m = 1; m < 16; m <<= 1) lsum += __shfl_xor(lsum, m, 64);
        if (j == 0) tot[team] = lsum;
    }
    __syncthreads();
    if (tid == 0) {
        unsigned run = 0;
        for (int p = 0; p < NPART; ++p) { bstart[p] = run; run += tot[p]; }
    }
    __syncthreads();
    if (tid < NPART) { binStartG[tid] = bstart[tid]; binTotalG[tid] = tot[tid]; }
    if (team < NPART) {
        const int per = NB / 16;   // 32
        unsigned ls = 0;
        for (int b = j * per; b < (j + 1) * per; ++b)
            ls += blockHist[(size_t)b * NPART + team];
        unsigned excl = 0;
        int waveBase = (team & 3) * 16;
        for (int k = 0; k < 16; ++k) {
            unsigned v = __shfl(ls, waveBase + k, 64);
            if (k < j) excl += v;
        }
        unsigned run = bstart[team] + excl;
        for (int b = j * per; b < (j + 1) * per; ++b) {
            offsets[(size_t)b * NPART + team] = run;
            run += blockHist[(size_t)b * NPART + team];
        }
    }
}

// Emit 16B records {s|d<<16, a, w, b} into partition bins (2 records if cross).
__global__ __launch_bounds__(TPB)
void scatter_kernel(const int* __restrict__ src, const int* __restrict__ des,
                    const float* __restrict__ param, const unsigned* __restrict__ offsets,
                    uint4* __restrict__ records, int E) {
    __shared__ unsigned offs[NPART];
    int tid = threadIdx.x;
    if (tid < NPART) offs[tid] = offsets[(size_t)blockIdx.x * NPART + tid];
    __syncthreads();
    long t = (long)blockIdx.x * TPB + tid;
    long stride = (long)gridDim.x * TPB * 4;
    for (long e0 = t * 4; e0 < E; e0 += stride) {
        int ne = (int)min((long)4, (long)E - e0);
        int ss[4], dd[4];
        float aa[4], ww[4], cc[4];
        if (ne == 4) {
            int4 sv = *(const int4*)(src + e0);
            int4 dv = *(const int4*)(des + e0);
            float4 av = *(const float4*)(param + e0);
            float4 wv = *(const float4*)(param + E + e0);
            float4 cv = *(const float4*)(param + 2 * (size_t)E + e0);
            ss[0]=sv.x; ss[1]=sv.y; ss[2]=sv.z; ss[3]=sv.w;
            dd[0]=dv.x; dd[1]=dv.y; dd[2]=dv.z; dd[3]=dv.w;
            aa[0]=av.x; aa[1]=av.y; aa[2]=av.z; aa[3]=av.w;
            ww[0]=wv.x; ww[1]=wv.y; ww[2]=wv.z; ww[3]=wv.w;
            cc[0]=cv.x; cc[1]=cv.y; cc[2]=cv.z; cc[3]=cv.w;
        } else {
            for (int j = 0; j < ne; ++j) {
                ss[j] = src[e0 + j]; dd[j] = des[e0 + j];
                aa[j] = param[e0 + j]; ww[j] = param[E + e0 + j];
                cc[j] = param[2 * (size_t)E + e0 + j];
            }
        }
        for (int j = 0; j < ne; ++j) {
            int s = ss[j], d = dd[j];
            uint4 rec = make_uint4((unsigned)s | ((unsigned)d << 16),
                                   __float_as_uint(aa[j]), __float_as_uint(ww[j]),
                                   __float_as_uint(cc[j]));
            int ps = s / PS, pd = d / PS;
            unsigned slot = atomicAdd(&offs[ps], 1u);
            records[slot] = rec;
            if (pd != ps) {
                unsigned slot2 = atomicAdd(&offs[pd], 1u);
                records[slot2] = rec;
            }
        }
    }
}

// Block (p, slice): 4 lanes per record, each lane owns 4 batches (float4).
// Aux gathers issued with sc0 (agent scope) -> bypass L1, served by L2.
__global__ __launch_bounds__(TPB, 8)
void accumulate_kernel(const uint4* __restrict__ records, const float* __restrict__ auxT,
                       const unsigned* __restrict__ binStart,
                       const unsigned* __restrict__ binTotal,
                       float* __restrict__ partials) {
    __shared__ float acc[PS * STRIDE];
    int p = blockIdx.x >> 3;          // / SLICES
    int sl = blockIdx.x & (SLICES - 1);
    int tid = threadIdx.x;
    for (int i = tid; i < PS * STRIDE; i += TPB) acc[i] = 0.0f;
    __syncthreads();
    unsigned bs = binStart[p], cnt = binTotal[p];
    unsigned lo = bs + (unsigned)(((unsigned long long)cnt * sl) / SLICES);
    unsigned hi = bs + (unsigned)(((unsigned long long)cnt * (sl + 1)) / SLICES);
    int base = p * PS;
    int g = tid >> 2;                 // 256 groups of 4 lanes
    int lj = tid & 3;                 // lane-in-group: batches 4*lj .. 4*lj+3
    const unsigned G = TPB / 4;       // 256
    const uint4v* recv = (const uint4v*)records;
    const float4* aux4 = (const float4*)auxT;   // row i = aux4[i*4 + lj]
    int bb = lj * 4;

    for (unsigned r = lo + g; r < hi; r += G) {
        uint4v rec = __builtin_nontemporal_load(&recv[r]);
        int s = (int)(rec.x & 0xFFFFu);
        int d = (int)(rec.x >> 16);
        const float4* ps_ = &aux4[s * 4 + lj];
        const float4* pd_ = &aux4[d * 4 + lj];
        float4v vs, vd;
        // Both gathers in flight together, L1 bypassed via agent-scope (sc0).
        asm volatile(
            "global_load_dwordx4 %0, %2, off sc0\n\t"
            "global_load_dwordx4 %1, %3, off sc0\n\t"
            "s_waitcnt vmcnt(0)"
            : "=&v"(vs), "=&v"(vd)
            : "v"(ps_), "v"(pd_)
            : "memory");
        float a = __uint_as_float(rec.y);
        float w = __uint_as_float(rec.z);
        float c = __uint_as_float(rec.w);
        float st0 = a * fast_tanh(w * (vs.x - vd.x) + c);
        float st1 = a * fast_tanh(w * (vs.y - vd.y) + c);
        float st2 = a * fast_tanh(w * (vs.z - vd.z) + c);
        float st3 = a * fast_tanh(w * (vs.w - vd.w) + c);
        unsigned ls = (unsigned)(s - base), ld = (unsigned)(d - base);
        if (ls < PS) {
            float* as_ = &acc[ls * STRIDE + bb];
            atomicAdd(as_ + 0, -st0);
            atomicAdd(as_ + 1, -st1);
            atomicAdd(as_ + 2, -st2);
            atomicAdd(as_ + 3, -st3);
        }
        if (ld < PS) {
            float* ad_ = &acc[ld * STRIDE + bb];
            atomicAdd(ad_ + 0, st0);
            atomicAdd(ad_ + 1, st1);
            atomicAdd(ad_ + 2, st2);
            atomicAdd(ad_ + 3, st3);
        }
    }
    __syncthreads();
    float* myPart = partials + (size_t)blockIdx.x * (PS * BATCH);
    for (int i = tid; i < PS * BATCH; i += TPB)
        myPart[i] = acc[(i >> 4) * STRIDE + (i & 15)];
}

// out[b][j] = sum_sl partials[p*SLICES+sl][local*16+b], node i=j+1
__global__ void reduce_sorted(const float* __restrict__ partials,
                              float* __restrict__ out, int n) {
    int idx = blockIdx.x * blockDim.x + threadIdx.x;
    if (idx >= BATCH * n) return;
    int b = idx / n;
    int j = idx % n;
    int i = j + 1;
    int p = i / PS;
    int local = i - p * PS;
    const float* basep = partials + (size_t)p * SLICES * (PS * BATCH)
                         + (size_t)local * BATCH + b;
    float sum = 0.0f;
#pragma unroll
    for (int sl = 0; sl < SLICES; ++sl) sum += basep[(size_t)sl * (PS * BATCH)];
    out[idx] = sum;
}

// ---------------- fallback: direct device atomics ----------------
__global__ void edge_direct(const float* __restrict__ param,
                            const int* __restrict__ src,
                            const int* __restrict__ des,
                            const float* __restrict__ x,
                            float* __restrict__ out, int E, int n) {
    int e = blockIdx.x * blockDim.x + threadIdx.x;
    if (e >= E) return;
    float a = param[e], w = param[E + e], c = param[2 * E + e];
    int s = src[e], d = des[e];
#pragma unroll
    for (int b = 0; b < BATCH; ++b) {
        float vs = s ? x[(size_t)b * n + (s - 1)] : 0.0f;
        float vd = d ? x[(size_t)b * n + (d - 1)] : 0.0f;
        float st = a * tanhf(w * (vs - vd) + c);
        if (s) atomicAdd(out + (size_t)b * n + (s - 1), -st);
        if (d) atomicAdd(out + (size_t)b * n + (d - 1), st);
    }
}

extern "C" void kernel_launch(void* const* d_in, const int* in_sizes, int n_in,
                              void* d_out, int out_size, void* d_ws, size_t ws_size,
                              hipStream_t stream) {
    const float* x     = (const float*)d_in[1];
    const float* param = (const float*)d_in[2];
    const int*   src   = (const int*)d_in[3];
    const int*   des   = (const int*)d_in[4];
    float* out = (float*)d_out;

    int E = in_sizes[3];
    int n = in_sizes[1] / BATCH;   // N = 50000
    int total = BATCH * n;

    auto alignup = [](size_t v) { return (v + 255) & ~(size_t)255; };
    size_t auxBytes     = alignup((size_t)(n + 1) * BATCH * sizeof(float));
    size_t recBytes     = alignup((size_t)2 * E * sizeof(uint4));
    size_t histBytes    = alignup((size_t)NB * NPART * sizeof(unsigned));
    size_t offBytes     = histBytes;
    size_t binBytes     = alignup((size_t)NPART * sizeof(unsigned));
    size_t partBytes    = alignup((size_t)NB * PS * BATCH * sizeof(float));
    size_t needSorted   = auxBytes + recBytes + histBytes + offBytes + 2 * binBytes + partBytes;

    if (ws_size >= needSorted && (n + 1) <= NPART * PS && n <= 65535) {
        char* w = (char*)d_ws;
        float*    auxT      = (float*)w;                 w += auxBytes;
        uint4*    records   = (uint4*)w;                 w += recBytes;
        unsigned* blockHist = (unsigned*)w;              w += histBytes;
        unsigned* offsets   = (unsigned*)w;              w += offBytes;
        unsigned* binStart  = (unsigned*)w;              w += binBytes;
        unsigned* binTotal  = (unsigned*)w;              w += binBytes;
        float*    partials  = (float*)w;

        build_aux_T<<<(total + 255) / 256, 256, 0, stream>>>(x, auxT, n);
        hist_kernel<<<NB, TPB, 0, stream>>>(src, des, blockHist, E);
        scan_offsets<<<1, TPB, 0, stream>>>(blockHist, offsets, binStart, binTotal);
        scatter_kernel<<<NB, TPB, 0, stream>>>(src, des, param, offsets, records, E);
        accumulate_kernel<<<NB, TPB, 0, stream>>>(records, auxT, binStart, binTotal, partials);
        reduce_sorted<<<(total + 255) / 256, 256, 0, stream>>>(partials, out, n);
        return;
    }

    (void)hipMemsetAsync(out, 0, (size_t)out_size * sizeof(float), stream);
    edge_direct<<<(E + 255) / 256, 256, 0, stream>>>(param, src, des, x, out, E, n);
}